// Round 4
// baseline (22825.194 us; speedup 1.0000x reference)
//
#include <hip/hip_runtime.h>

typedef float f4 __attribute__((ext_vector_type(4)));

#define Nn 256
#define Mm 512
#define Dd 64
#define EPSF 1e-6f
#define INFF 1e30f
#define BC 8
#define NCHUNK (Nn / BC)   // 32
#define R 16               // rows per wave-stage
#define NBLK 2             // pipeline groups (blocks) -> ONE LLC boundary
#define WVS 16             // waves per block (1024 threads)
#define SST (NBLK * WVS)   // 32 stages total
#define SLOTS 16           // LDS slice ring depth (must be >= WVS)

// workspace layout (float offsets)
#define OFF_D     0                    // d[m][n]        512*256
#define OFF_QC    131072               // qc[nb][j]=q[j][nb]  256*257
#define OFF_P     (OFF_QC + 65792)     // p[257]
#define OFF_WT    (OFF_P + 260)        // wT[t][n]=w[n][t]    256*256
#define OFF_WS    (OFF_WT + 65536)     // W[n] column sums    256
#define OFF_CBAR  (OFF_WS + 256)       // inter-block Cbar slices 256*256
#define OFF_CROW  (OFF_CBAR + 65536)   // C row handoffs, NBLK*256 (region sized SST*Nn)
#define OFF_FLAG  (OFF_CROW + SST*Nn)  // flags[blk][chunk], NBLK*NCHUNK ints

// ---------------- LLC-coherent (sc0 sc1) access helpers ----------------
__device__ __forceinline__ int llc_load_int(const int* p) {
  int v;
  asm volatile("global_load_dword %0, %1, off sc0 sc1\n\ts_waitcnt vmcnt(0)"
               : "=v"(v) : "v"(p) : "memory");
  return v;
}
__device__ __forceinline__ void llc_store_int(int* p, int v) {
  asm volatile("global_store_dword %0, %1, off sc0 sc1" :: "v"(p), "v"(v) : "memory");
}
// 8 cbar rows + 2 crow vectors in one round trip — block boundary load
__device__ __forceinline__ void llc_load_cbar10(const float* b0, const float* cp,
                                                f4 c[8], f4& pl, f4& ph) {
  const float* b1 = b0 + 4 * Nn;
  asm volatile(
    "global_load_dwordx4 %0, %10, off sc0 sc1\n\t"
    "global_load_dwordx4 %1, %10, off offset:1024 sc0 sc1\n\t"
    "global_load_dwordx4 %2, %10, off offset:2048 sc0 sc1\n\t"
    "global_load_dwordx4 %3, %10, off offset:3072 sc0 sc1\n\t"
    "global_load_dwordx4 %4, %11, off sc0 sc1\n\t"
    "global_load_dwordx4 %5, %11, off offset:1024 sc0 sc1\n\t"
    "global_load_dwordx4 %6, %11, off offset:2048 sc0 sc1\n\t"
    "global_load_dwordx4 %7, %11, off offset:3072 sc0 sc1\n\t"
    "global_load_dwordx4 %8, %12, off sc0 sc1\n\t"
    "global_load_dwordx4 %9, %12, off offset:16 sc0 sc1\n\t"
    "s_waitcnt vmcnt(0)"
    : "=v"(c[0]), "=v"(c[1]), "=v"(c[2]), "=v"(c[3]),
      "=v"(c[4]), "=v"(c[5]), "=v"(c[6]), "=v"(c[7]),
      "=v"(pl), "=v"(ph)
    : "v"(b0), "v"(b1), "v"(cp)
    : "memory");
}
__device__ __forceinline__ void llc_store_cbar8(float* b0, const f4 c[8]) {
  float* b1 = b0 + 4 * Nn;
  asm volatile(
    "global_store_dwordx4 %8, %0, off sc0 sc1\n\t"
    "global_store_dwordx4 %8, %1, off offset:1024 sc0 sc1\n\t"
    "global_store_dwordx4 %8, %2, off offset:2048 sc0 sc1\n\t"
    "global_store_dwordx4 %8, %3, off offset:3072 sc0 sc1\n\t"
    "global_store_dwordx4 %9, %4, off sc0 sc1\n\t"
    "global_store_dwordx4 %9, %5, off offset:1024 sc0 sc1\n\t"
    "global_store_dwordx4 %9, %6, off offset:2048 sc0 sc1\n\t"
    "global_store_dwordx4 %9, %7, off offset:3072 sc0 sc1\n\t"
    "s_waitcnt vmcnt(0)"
    :: "v"(c[0]), "v"(c[1]), "v"(c[2]), "v"(c[3]),
       "v"(c[4]), "v"(c[5]), "v"(c[6]), "v"(c[7]),
       "v"(b0), "v"(b1)
    : "memory");
}
__device__ __forceinline__ float rdlane(float v, int l) {
  return __int_as_float(__builtin_amdgcn_readlane(__float_as_int(v), l));
}

// ---------------- fused setup: dist (b<512) | qt (b<769) | init (b==769) ----------------
__global__ __launch_bounds__(256) void k_pre(const float* __restrict__ x,
                                             const float* __restrict__ y,
                                             const float* __restrict__ q,
                                             float* __restrict__ ws) {
  const int b = blockIdx.x, t = threadIdx.x;
  if (b < Mm) {
    __shared__ float xs[Dd];
    if (t < Dd) xs[t] = x[b * Dd + t];
    __syncthreads();
    const float4* y4 = (const float4*)(y + t * Dd);
    float acc = 0.f;
#pragma unroll
    for (int k = 0; k < Dd / 4; k++) {
      float4 v = y4[k];
      float a0 = xs[4*k+0] - v.x, a1 = xs[4*k+1] - v.y;
      float a2 = xs[4*k+2] - v.z, a3 = xs[4*k+3] - v.w;
      acc += a0*a0 + a1*a1 + a2*a2 + a3*a3;
    }
    ws[OFF_D + b * Nn + t] = sqrtf(acc);
  } else if (b < Mm + 257) {
    const int j = b - Mm;                 // qc[nb][j] = q[j][nb]
    ws[OFF_QC + t * 257 + j] = q[j * Nn + t];
  } else {
    ws[OFF_WS + t] = 0.f;
    if (t < NBLK * NCHUNK) ((int*)(ws + OFF_FLAG))[t] = 0;
  }
}

__global__ __launch_bounds__(256) void k_reach(const float* __restrict__ qc, float* __restrict__ p_out) {
  __shared__ float p[257];
  __shared__ float vsnap[64];
  __shared__ float qtile[64][65];
  int tid = threadIdx.x;
  p[tid] = (tid == 0) ? 1.f : 0.f;
  if (tid == 0) p[256] = 0.f;
  __syncthreads();
  for (int g = 0; g < 4; g++) {
    int g0 = g * 64;
    for (int z = 0; z < 16; z++) {
      int idx = tid + z * 256, k = idx >> 6, l = idx & 63;
      qtile[k][l] = qc[(g0 + k) * 257 + g0 + l];
    }
    __syncthreads();
    if (tid < 64) {
      float pv = p[g0 + tid];
      for (int k = 0; k < 64; k++) {
        float v = __shfl(pv, k, 64);
        if (tid == k) vsnap[k] = v;
        pv += v * qtile[k][tid];
      }
    }
    __syncthreads();
    float acc = p[tid];
    float acc2 = (tid == 0) ? p[256] : 0.f;
    for (int k = 0; k < 64; k++) {
      float v = vsnap[k];
      acc += v * qc[(g0 + k) * 257 + tid];
      if (tid == 0) acc2 += v * qc[(g0 + k) * 257 + 256];
    }
    __syncthreads();
    p[tid] = acc;
    if (tid == 0) p[256] = acc2;
    __syncthreads();
  }
  p_out[tid] = p[tid];
  if (tid == 0) p_out[256] = p[256];
}

__global__ __launch_bounds__(256) void k_wbuild(const float* __restrict__ qc, const float* __restrict__ p,
                                                float* __restrict__ wT, float* __restrict__ Wsum) {
  int t = blockIdx.x, n = threadIdx.x;
  float v = 0.f;
  if (t < n) v = p[t] * qc[t * 257 + n] / (p[n] + EPSF);
  wT[t * Nn + n] = v;
  if (v != 0.f) atomicAdd(&Wsum[n], v);
}

// ---------------- main systolic DP: 2 blocks x 16 waves, barrier-stepped pipeline ----------------
// Round-2 protocol exactly (blocking sc0sc1 poll + payload, in-step publish), but only ONE
// inter-block LLC boundary. Step s: wave w processes chunk j = s - w; __syncthreads() every
// step by ALL waves -> deadlock-free. Slot (s-w) mod 16 is touched by exactly one wave per
// step (in-place update); producer->consumer separated by one barrier; reuse distance 16.
__global__ __launch_bounds__(1024, 1) void k_main(const float* __restrict__ d,
                                                  const float* __restrict__ wT,
                                                  const float* __restrict__ Wsum,
                                                  float* __restrict__ cbarG,
                                                  float* __restrict__ crowG,
                                                  int* __restrict__ flags) {
  __shared__ __align__(16) float sbuf[SLOTS][BC * Nn];       // 128 KB slice ring
  __shared__ __align__(16) float crow_lds[WVS][SLOTS][BC];   // 8 KB crow handoffs

  const int tid  = threadIdx.x;
  const int wave = tid >> 6;         // 0..15: stage within block
  const int lane = tid & 63;         // owns columns 4*lane .. 4*lane+3
  const int blk  = blockIdx.x;
  const int stage = blk * WVS + wave;
  const int m0 = stage * R;

  f4 dl[R], S[R];
#pragma unroll
  for (int r = 0; r < R; r++) {
    dl[r] = *(const f4*)(d + (m0 + r) * Nn + 4 * lane);
    S[r] = (f4){0.f, 0.f, 0.f, 0.f};
  }
  f4 Wt = *(const f4*)(Wsum + 4 * lane);

#pragma clang loop unroll(disable)
  for (int s = 0; s < NCHUNK + WVS - 1; s++) {
    const int j = s - wave;
    if (j >= 0 && j < NCHUNK) {
      // wT chunk: plain cached loads (read-only, L2-resident) — issue before any wait
      f4 wv[BC];
#pragma unroll
      for (int tt = 0; tt < BC; tt++)
        wv[tt] = *(const f4*)(wT + (j * BC + tt) * Nn + 4 * lane);

      f4 c[BC], cpl, cph;
      float* lsl = &sbuf[j & (SLOTS - 1)][0] + 4 * lane;

      if (wave == 0) {
        if (blk > 0) {
          const int* fp = flags + (blk - 1) * NCHUNK + j;
          while (llc_load_int(fp) == 0) __builtin_amdgcn_s_sleep(1);
          llc_load_cbar10(cbarG + (size_t)j * BC * Nn + 4 * lane,
                          crowG + (blk - 1) * Nn + j * BC, c, cpl, cph);
        } else {
          cpl = (f4){INFF, INFF, INFF, INFF};
          cph = cpl;
#pragma unroll
          for (int tt = 0; tt < BC; tt++) c[tt] = cpl;
        }
      } else {
        // slice written by wave-1 at step s-1 (barrier-separated)
#pragma unroll
        for (int tt = 0; tt < BC; tt++) c[tt] = *(const f4*)(lsl + tt * Nn);
        const float* cr = &crow_lds[wave - 1][j & (SLOTS - 1)][0];
        cpl = *(const f4*)cr;
        cph = *(const f4*)(cr + 4);
      }

      f4 clast4;
      const bool isJ0 = (j == 0);
#pragma unroll
      for (int tt = 0; tt < BC; tt++) {
        const int owner = 2 * j + (tt >> 2);   // wave-uniform
        const int comp = tt & 3;               // == t & 3 (compile-time)
        const bool isT0 = isJ0 && (tt == 0);

        float up = (tt < 4) ? cpl[comp] : cph[comp];   // upstream C[m0-1][t]
        float prcMin = up;                              // for cmin2
        float prcVal = up;                              // for the t==0 value chain
        if (isT0 && stage == 0) prcVal = 0.f;
        float cml[R];
#pragma unroll
        for (int r = 0; r < R; r++) {
          float Cv;
          if (isT0) Cv = dl[r][0] + prcVal;                       // C[m][0] = d + C[m-1][0]
          else      Cv = fmaf(dl[r][comp], Wt[comp], S[r][comp]); // C[m][t] = d*W + S
          cml[r] = fminf(Cv, prcMin);                             // cmin2 = min(C[m][t], C[m-1][t])
          prcVal = Cv;
          prcMin = Cv;
        }
        // broadcast owner lane's cmin2 chain + last-row C to all lanes
        float cmB[R];
#pragma unroll
        for (int r = 0; r < R; r++) cmB[r] = rdlane(cml[r], owner);
        float clastv = rdlane(prcVal, owner);
        if (lane == owner) clast4[comp] = clastv;

        // stream update: for each owned column n, chain Cbar through 16 rows
#pragma unroll
        for (int k = 0; k < 4; k++) {
          float w_ = wv[tt][k];
          if (w_ > 0.f) {
            float cbv = c[tt][k];
#pragma unroll
            for (int r = 0; r < R; r++) {
              float a = fminf(cmB[r], cbv);
              S[r][k] = fmaf(w_, a, S[r][k]);
              cbv = dl[r][k] + a;
            }
            c[tt][k] = cbv;
          }
        }
      }

      // ---- handoff ----
      if (wave < WVS - 1) {
        // intra-block: write slice + crow to LDS; consumer reads after next barrier
#pragma unroll
        for (int tt = 0; tt < BC; tt++) *(f4*)(lsl + tt * Nn) = c[tt];
        if (lane == 2 * j || lane == 2 * j + 1)
          *(f4*)&crow_lds[wave][j & (SLOTS - 1)][(lane & 1) * 4] = clast4;
      } else {
        // last wave: inter-block handoff via LLC (round-2 in-step publish)
        if (lane == 2 * j || lane == 2 * j + 1) {
          float* cp = crowG + blk * Nn + j * BC + (lane & 1) * 4;
          asm volatile("global_store_dwordx4 %0, %1, off sc0 sc1" :: "v"(cp), "v"(clast4) : "memory");
        }
        if (blk < NBLK - 1) {
          llc_store_cbar8(cbarG + (size_t)j * BC * Nn + 4 * lane, c); // vmcnt(0) covers crow too
          if (lane == 0) llc_store_int(flags + blk * NCHUNK + j, 1);
        } else {
          asm volatile("s_waitcnt vmcnt(0)" ::: "memory");  // drain crow store for k_final
        }
      }
    }
    __syncthreads();
  }
}

__global__ __launch_bounds__(256) void k_final(const float* __restrict__ q, const float* __restrict__ p,
                                               const float* __restrict__ crowG, float* __restrict__ out) {
  __shared__ float red[256];
  int n = threadIdx.x;
  float c = crowG[(NBLK - 1) * Nn + n];
  float fw = p[n] * q[Nn * Nn + n] / (p[Nn] + EPSF);
  red[n] = fw * c;
  __syncthreads();
  for (int sft = 128; sft > 0; sft >>= 1) {
    if (n < sft) red[n] += red[n + sft];
    __syncthreads();
  }
  if (n == 0) out[0] = red[0];
}

extern "C" void kernel_launch(void* const* d_in, const int* in_sizes, int n_in,
                              void* d_out, int out_size, void* d_ws, size_t ws_size,
                              hipStream_t stream) {
  const float* x = (const float*)d_in[0];
  const float* y = (const float*)d_in[1];
  const float* q = (const float*)d_in[2];
  float* ws = (float*)d_ws;
  float* out = (float*)d_out;
  hipLaunchKernelGGL(k_pre,   dim3(Mm + 257 + 1), dim3(256), 0, stream, x, y, q, ws);
  hipLaunchKernelGGL(k_reach, dim3(1),   dim3(256), 0, stream, ws + OFF_QC, ws + OFF_P);
  hipLaunchKernelGGL(k_wbuild,dim3(Nn),  dim3(Nn),  0, stream, ws + OFF_QC, ws + OFF_P,
                     ws + OFF_WT, ws + OFF_WS);
  hipLaunchKernelGGL(k_main,  dim3(NBLK), dim3(1024), 0, stream, ws + OFF_D, ws + OFF_WT,
                     ws + OFF_WS, ws + OFF_CBAR, ws + OFF_CROW, (int*)(ws + OFF_FLAG));
  hipLaunchKernelGGL(k_final, dim3(1),   dim3(256), 0, stream, q, ws + OFF_P, ws + OFF_CROW, out);
}

// Round 8
// 493.864 us; speedup vs baseline: 46.2176x; 46.2176x over previous
//
#include <hip/hip_runtime.h>

typedef float f4 __attribute__((ext_vector_type(4)));

#define Nn 256
#define Mm 512
#define Dd 64
#define EPSF 1e-6f
#define INFF 1e30f
#define BC 8
#define NCHUNK (Nn / BC)   // 32
#define R 16               // rows per wave-stage
#define NBLK 8             // pipeline groups (blocks)
#define CW 4               // compute waves per block
#define SST (NBLK * CW)    // 32 stages total
#define SLOTS 4            // LDS slice ring depth

// workspace layout (float offsets)
#define OFF_D     0                    // d[m][n]        512*256
#define OFF_QC    131072               // qc[nb][j]=q[j][nb]  256*257
#define OFF_P     (OFF_QC + 65792)     // p[257]
#define OFF_WT    (OFF_P + 260)        // wT[t][n]=w[n][t]    256*256
#define OFF_WS    (OFF_WT + 65536)     // W[n] column sums    256
#define OFF_CBAR  (OFF_WS + 256)       // inter-block Cbar slices 256*256
#define OFF_CROW  (OFF_CBAR + 65536)   // C row handoffs (region sized SST*Nn)
#define OFF_FLAG  (OFF_CROW + SST*Nn)  // flags[blk][chunk], NBLK*NCHUNK ints

// ---------------- LLC-coherent (sc0 sc1) access helpers — proven round-2 forms ----------------
__device__ __forceinline__ int llc_load_int(const int* p) {
  int v;
  asm volatile("global_load_dword %0, %1, off sc0 sc1\n\ts_waitcnt vmcnt(0)"
               : "=v"(v) : "v"(p) : "memory");
  return v;
}
__device__ __forceinline__ void llc_store_int(int* p, int v) {
  asm volatile("global_store_dword %0, %1, off sc0 sc1" :: "v"(p), "v"(v) : "memory");
}
// blocking: 8 cbar rows + 2 crow vectors, wait until complete
__device__ __forceinline__ void llc_load_cbar10(const float* b0, const float* cp,
                                                f4 c[8], f4& pl, f4& ph) {
  const float* b1 = b0 + 4 * Nn;
  asm volatile(
    "global_load_dwordx4 %0, %10, off sc0 sc1\n\t"
    "global_load_dwordx4 %1, %10, off offset:1024 sc0 sc1\n\t"
    "global_load_dwordx4 %2, %10, off offset:2048 sc0 sc1\n\t"
    "global_load_dwordx4 %3, %10, off offset:3072 sc0 sc1\n\t"
    "global_load_dwordx4 %4, %11, off sc0 sc1\n\t"
    "global_load_dwordx4 %5, %11, off offset:1024 sc0 sc1\n\t"
    "global_load_dwordx4 %6, %11, off offset:2048 sc0 sc1\n\t"
    "global_load_dwordx4 %7, %11, off offset:3072 sc0 sc1\n\t"
    "global_load_dwordx4 %8, %12, off sc0 sc1\n\t"
    "global_load_dwordx4 %9, %12, off offset:16 sc0 sc1\n\t"
    "s_waitcnt vmcnt(0)"
    : "=v"(c[0]), "=v"(c[1]), "=v"(c[2]), "=v"(c[3]),
      "=v"(c[4]), "=v"(c[5]), "=v"(c[6]), "=v"(c[7]),
      "=v"(pl), "=v"(ph)
    : "v"(b0), "v"(b1), "v"(cp)
    : "memory");
}
__device__ __forceinline__ void llc_store_cbar8(float* b0, const f4 c[8]) {
  float* b1 = b0 + 4 * Nn;
  asm volatile(
    "global_store_dwordx4 %8, %0, off sc0 sc1\n\t"
    "global_store_dwordx4 %8, %1, off offset:1024 sc0 sc1\n\t"
    "global_store_dwordx4 %8, %2, off offset:2048 sc0 sc1\n\t"
    "global_store_dwordx4 %8, %3, off offset:3072 sc0 sc1\n\t"
    "global_store_dwordx4 %9, %4, off sc0 sc1\n\t"
    "global_store_dwordx4 %9, %5, off offset:1024 sc0 sc1\n\t"
    "global_store_dwordx4 %9, %6, off offset:2048 sc0 sc1\n\t"
    "global_store_dwordx4 %9, %7, off offset:3072 sc0 sc1\n\t"
    "s_waitcnt vmcnt(0)"
    :: "v"(c[0]), "v"(c[1]), "v"(c[2]), "v"(c[3]),
       "v"(c[4]), "v"(c[5]), "v"(c[6]), "v"(c[7]),
       "v"(b0), "v"(b1)
    : "memory");
}
__device__ __forceinline__ float rdlane(float v, int l) {
  return __int_as_float(__builtin_amdgcn_readlane(__float_as_int(v), l));
}

// ---------------- fused setup: dist (b<512) | qt (b<769) | init (b==769) ----------------
__global__ __launch_bounds__(256) void k_pre(const float* __restrict__ x,
                                             const float* __restrict__ y,
                                             const float* __restrict__ q,
                                             float* __restrict__ ws) {
  const int b = blockIdx.x, t = threadIdx.x;
  if (b < Mm) {
    __shared__ float xs[Dd];
    if (t < Dd) xs[t] = x[b * Dd + t];
    __syncthreads();
    const float4* y4 = (const float4*)(y + t * Dd);
    float acc = 0.f;
#pragma unroll
    for (int k = 0; k < Dd / 4; k++) {
      float4 v = y4[k];
      float a0 = xs[4*k+0] - v.x, a1 = xs[4*k+1] - v.y;
      float a2 = xs[4*k+2] - v.z, a3 = xs[4*k+3] - v.w;
      acc += a0*a0 + a1*a1 + a2*a2 + a3*a3;
    }
    ws[OFF_D + b * Nn + t] = sqrtf(acc);
  } else if (b < Mm + 257) {
    const int j = b - Mm;                 // qc[nb][j] = q[j][nb]
    ws[OFF_QC + t * 257 + j] = q[j * Nn + t];
  } else {
    ws[OFF_WS + t] = 0.f;
    if (t < NBLK * NCHUNK) ((int*)(ws + OFF_FLAG))[t] = 0;
  }
}

__global__ __launch_bounds__(256) void k_reach(const float* __restrict__ qc, float* __restrict__ p_out) {
  __shared__ float p[257];
  __shared__ float vsnap[64];
  __shared__ float qtile[64][65];
  int tid = threadIdx.x;
  p[tid] = (tid == 0) ? 1.f : 0.f;
  if (tid == 0) p[256] = 0.f;
  __syncthreads();
  for (int g = 0; g < 4; g++) {
    int g0 = g * 64;
    for (int z = 0; z < 16; z++) {
      int idx = tid + z * 256, k = idx >> 6, l = idx & 63;
      qtile[k][l] = qc[(g0 + k) * 257 + g0 + l];
    }
    __syncthreads();
    if (tid < 64) {
      float pv = p[g0 + tid];
      for (int k = 0; k < 64; k++) {
        float v = __shfl(pv, k, 64);
        if (tid == k) vsnap[k] = v;
        pv += v * qtile[k][tid];
      }
    }
    __syncthreads();
    float acc = p[tid];
    float acc2 = (tid == 0) ? p[256] : 0.f;
    for (int k = 0; k < 64; k++) {
      float v = vsnap[k];
      acc += v * qc[(g0 + k) * 257 + tid];
      if (tid == 0) acc2 += v * qc[(g0 + k) * 257 + 256];
    }
    __syncthreads();
    p[tid] = acc;
    if (tid == 0) p[256] = acc2;
    __syncthreads();
  }
  p_out[tid] = p[tid];
  if (tid == 0) p_out[256] = p[256];
}

__global__ __launch_bounds__(256) void k_wbuild(const float* __restrict__ qc, const float* __restrict__ p,
                                                float* __restrict__ wT, float* __restrict__ Wsum) {
  int t = blockIdx.x, n = threadIdx.x;
  float v = 0.f;
  if (t < n) v = p[t] * qc[t * 257 + n] / (p[n] + EPSF);
  wT[t * Nn + n] = v;
  if (v != 0.f) atomicAdd(&Wsum[n], v);
}

// ---------------- main systolic DP: 8 blocks x (4 compute + 1 prefetch) waves ----------------
// Round-2 protocol; the ONLY change: the blocking poll + payload load for the inter-block
// boundary is executed by a dedicated prefetch wave (wave CW), one chunk ahead, staged
// through an LDS double-buffer. Registers from the asm loads are consumed into LDS stores
// within the same step (no cross-step register liveness). Producer side unchanged.
__global__ __launch_bounds__(320, 1) void k_main(const float* __restrict__ d,
                                                 const float* __restrict__ wT,
                                                 const float* __restrict__ Wsum,
                                                 float* __restrict__ cbarG,
                                                 float* __restrict__ crowG,
                                                 int* __restrict__ flags,
                                                 const float* __restrict__ q,
                                                 const float* __restrict__ p,
                                                 float* __restrict__ out) {
  __shared__ __align__(16) float sbuf[SLOTS][BC * Nn];       // 32 KB slice ring
  __shared__ __align__(16) float stg[2][BC * Nn];            // 16 KB boundary staging
  __shared__ __align__(16) float stg_cr[2][8];               // staged upstream crow
  __shared__ __align__(16) float crow_lds[CW][SLOTS][BC];    // intra-block crow handoffs
  __shared__ __align__(16) float crow_fin[Nn];               // last block: C_last stash

  const int tid  = threadIdx.x;
  const int wave = tid >> 6;         // 0..3 compute, 4 = prefetch
  const int lane = tid & 63;         // owns columns 4*lane .. 4*lane+3
  const int blk  = blockIdx.x;
  const int stage = blk * CW + wave;
  const int m0 = stage * R;

  f4 dl[R], S[R], Wt;
  if (wave < CW) {
#pragma unroll
    for (int r = 0; r < R; r++) {
      dl[r] = *(const f4*)(d + (m0 + r) * Nn + 4 * lane);
      S[r] = (f4){0.f, 0.f, 0.f, 0.f};
    }
    Wt = *(const f4*)(Wsum + 4 * lane);
  }

  // ---- prefetch prologue: stage chunk 0 (blocking, off compute waves' path) ----
  if (wave == CW && blk > 0) {
    const int* fp = flags + (blk - 1) * NCHUNK;
    while (llc_load_int(fp) == 0) __builtin_amdgcn_s_sleep(1);
    f4 c0[BC], pl, ph;
    llc_load_cbar10(cbarG + 4 * lane, crowG + (blk - 1) * Nn, c0, pl, ph);
#pragma unroll
    for (int tt = 0; tt < BC; tt++) *(f4*)&stg[0][tt * Nn + 4 * lane] = c0[tt];
    if (lane == 0) { *(f4*)&stg_cr[0][0] = pl; *(f4*)&stg_cr[0][4] = ph; }
  }
  __syncthreads();

#pragma clang loop unroll(disable)
  for (int s = 0; s < NCHUNK + CW - 1; s++) {
    if (wave < CW) {
      const int j = s - wave;
      if (j >= 0 && j < NCHUNK) {
        // wT chunk: plain cached loads (read-only, L2-resident)
        f4 wv[BC];
#pragma unroll
        for (int tt = 0; tt < BC; tt++)
          wv[tt] = *(const f4*)(wT + (j * BC + tt) * Nn + 4 * lane);

        f4 c[BC], cpl, cph;
        float* lsl = &sbuf[j & (SLOTS - 1)][0] + 4 * lane;

        if (wave == 0) {
          if (blk > 0) {
            // boundary payload staged by prefetch wave at step j-1 (barrier-separated)
#pragma unroll
            for (int tt = 0; tt < BC; tt++) c[tt] = *(const f4*)&stg[j & 1][tt * Nn + 4 * lane];
            cpl = *(const f4*)&stg_cr[j & 1][0];
            cph = *(const f4*)&stg_cr[j & 1][4];
          } else {
            cpl = (f4){INFF, INFF, INFF, INFF};
            cph = cpl;
#pragma unroll
            for (int tt = 0; tt < BC; tt++) c[tt] = cpl;
          }
        } else {
          // slice written by wave-1 at step s-1 (barrier-separated)
#pragma unroll
          for (int tt = 0; tt < BC; tt++) c[tt] = *(const f4*)(lsl + tt * Nn);
          const float* cr = &crow_lds[wave - 1][j & (SLOTS - 1)][0];
          cpl = *(const f4*)cr;
          cph = *(const f4*)(cr + 4);
        }

        f4 clast4;
        const bool isJ0 = (j == 0);
#pragma unroll
        for (int tt = 0; tt < BC; tt++) {
          const int owner = 2 * j + (tt >> 2);   // wave-uniform
          const int comp = tt & 3;               // == t & 3 (compile-time)
          const bool isT0 = isJ0 && (tt == 0);

          float up = (tt < 4) ? cpl[comp] : cph[comp];   // upstream C[m0-1][t]
          float prcMin = up;                              // for cmin2
          float prcVal = up;                              // for the t==0 value chain
          if (isT0 && stage == 0) prcVal = 0.f;
          float cml[R];
#pragma unroll
          for (int r = 0; r < R; r++) {
            float Cv;
            if (isT0) Cv = dl[r][0] + prcVal;                       // C[m][0] = d + C[m-1][0]
            else      Cv = fmaf(dl[r][comp], Wt[comp], S[r][comp]); // C[m][t] = d*W + S
            cml[r] = fminf(Cv, prcMin);                             // cmin2 = min(C[m][t], C[m-1][t])
            prcVal = Cv;
            prcMin = Cv;
          }
          // broadcast owner lane's cmin2 chain + last-row C to all lanes
          float cmB[R];
#pragma unroll
          for (int r = 0; r < R; r++) cmB[r] = rdlane(cml[r], owner);
          float clastv = rdlane(prcVal, owner);
          if (lane == owner) clast4[comp] = clastv;

          // stream update: for each owned column n, chain Cbar through 16 rows
#pragma unroll
          for (int k = 0; k < 4; k++) {
            float w_ = wv[tt][k];
            if (w_ > 0.f) {
              float cbv = c[tt][k];
#pragma unroll
              for (int r = 0; r < R; r++) {
                float a = fminf(cmB[r], cbv);
                S[r][k] = fmaf(w_, a, S[r][k]);
                cbv = dl[r][k] + a;
              }
              c[tt][k] = cbv;
            }
          }
        }

        // ---- handoff ----
        if (wave < CW - 1) {
          // intra-block: write slice + crow to LDS; consumer reads after next barrier
#pragma unroll
          for (int tt = 0; tt < BC; tt++) *(f4*)(lsl + tt * Nn) = c[tt];
          if (lane == 2 * j || lane == 2 * j + 1)
            *(f4*)&crow_lds[wave][j & (SLOTS - 1)][(lane & 1) * 4] = clast4;
        } else if (blk < NBLK - 1) {
          // last compute wave: inter-block handoff via LLC (round-2 in-step publish)
          if (lane == 2 * j || lane == 2 * j + 1) {
            float* cp = crowG + blk * Nn + j * BC + (lane & 1) * 4;
            asm volatile("global_store_dwordx4 %0, %1, off sc0 sc1" :: "v"(cp), "v"(clast4) : "memory");
          }
          llc_store_cbar8(cbarG + (size_t)j * BC * Nn + 4 * lane, c); // vmcnt(0) covers crow too
          if (lane == 0) llc_store_int(flags + blk * NCHUNK + j, 1);
        } else {
          // final stage: stash C_last into LDS for the fused reduction
          if (lane == 2 * j || lane == 2 * j + 1)
            *(f4*)&crow_fin[j * BC + (lane & 1) * 4] = clast4;
        }
      }
    } else {
      // ---- prefetch wave: stage chunk s+1 while compute waves work on s, s-1, ... ----
      const int jn = s + 1;
      if (blk > 0 && jn < NCHUNK) {
        const int* fp = flags + (blk - 1) * NCHUNK + jn;
        while (llc_load_int(fp) == 0) __builtin_amdgcn_s_sleep(1);
        f4 cn[BC], pl, ph;
        llc_load_cbar10(cbarG + (size_t)jn * BC * Nn + 4 * lane,
                        crowG + (blk - 1) * Nn + jn * BC, cn, pl, ph);
#pragma unroll
        for (int tt = 0; tt < BC; tt++) *(f4*)&stg[jn & 1][tt * Nn + 4 * lane] = cn[tt];
        if (lane == 0) { *(f4*)&stg_cr[jn & 1][0] = pl; *(f4*)&stg_cr[jn & 1][4] = ph; }
      }
    }
    __syncthreads();
  }

  // ---- fused final reduction (last block only): out = sum_n p_back[N][n] * C_last[n] ----
  if (blk == NBLK - 1) {
    if (tid < Nn) {
      float fw = p[tid] * q[Nn * Nn + tid] / (p[Nn] + EPSF);
      crow_fin[tid] *= fw;
    }
    __syncthreads();
    for (int sft = 128; sft > 0; sft >>= 1) {
      if (tid < sft) crow_fin[tid] += crow_fin[tid + sft];
      __syncthreads();
    }
    if (tid == 0) out[0] = crow_fin[0];
  }
}

extern "C" void kernel_launch(void* const* d_in, const int* in_sizes, int n_in,
                              void* d_out, int out_size, void* d_ws, size_t ws_size,
                              hipStream_t stream) {
  const float* x = (const float*)d_in[0];
  const float* y = (const float*)d_in[1];
  const float* q = (const float*)d_in[2];
  float* ws = (float*)d_ws;
  float* out = (float*)d_out;
  hipLaunchKernelGGL(k_pre,   dim3(Mm + 257 + 1), dim3(256), 0, stream, x, y, q, ws);
  hipLaunchKernelGGL(k_reach, dim3(1),   dim3(256), 0, stream, ws + OFF_QC, ws + OFF_P);
  hipLaunchKernelGGL(k_wbuild,dim3(Nn),  dim3(256), 0, stream, ws + OFF_QC, ws + OFF_P,
                     ws + OFF_WT, ws + OFF_WS);
  hipLaunchKernelGGL(k_main,  dim3(NBLK), dim3(320), 0, stream, ws + OFF_D, ws + OFF_WT,
                     ws + OFF_WS, ws + OFF_CBAR, ws + OFF_CROW, (int*)(ws + OFF_FLAG),
                     q, ws + OFF_P, out);
}